// Round 3
// baseline (139.198 us; speedup 1.0000x reference)
//
#include <hip/hip_runtime.h>

// Bilateral 5x5, 3 chained passes. [32,1,512,512] fp32, replicate padding,
// w = exp2(dr^2*nax + dc^2*nay + d^2*ncr).
//
// Round-11: 2 launches. Round-10 de-fused into 3 clean passes; per-kernel
// time dropped below the profiler's top-5 cutoff (<43us, was 80us), and the
// profile is now dominated by the harness's 268MB workspace re-poison
// (fillBufferAligned, 45us/iter) plus launch/round-trip plumbing -- bench
// only moved 144->137.6us. Remaining controllable cost: launches (2 gaps)
// and inter-pass HBM round-trips (2 x 67MB ~ 22us). Fusing ONLY passes 2+3
// costs 1.17x compute overscan (2736+2048 px per 2048 useful, vs 3.98x for
// the old fused-3 design) and removes one launch + one full round-trip:
//   kernel A: pass1 in -> ws           (15us, unchanged structure)
//   kernel B: fused pass2+3 ws -> out  (stage 40x84 -> p2 into 36x76 LDS
//             -> replicate_fill -> p3 -> global), 24.4KB LDS, 6 blocks/CU.
// Fused-3 kernel kept as fallback if ws can't hold one intermediate image.
//
// Pruning (round 3): taps with spatial log2-weight < TH2 skipped via
// block-uniform branches -> effective 3x3 for sigma=0.5 (8 exps/px).
// Generic 5x5 path kept for large sigma.

typedef float v2f __attribute__((ext_vector_type(2)));

#define EXP2(x) __builtin_amdgcn_exp2f(x)
#define RCP(x)  __builtin_amdgcn_rcpf(x)
#define TH2 (-10.0f)

#define TILE_X 64
#define TILE_Y 32

// ---------------- shared tap core (validated rounds 8-10) ----------------

// Build 6-wide window row (cols c-1 .. c+4) from 3 aligned b128 quads.
__device__ __forceinline__ void mkrow6(const float* p, float* w6)
{
    const float4 L = *(const float4*)(p - 4);
    const float4 M = *(const float4*)(p);
    const float4 R = *(const float4*)(p + 4);
    w6[0] = L.w; w6[1] = M.x; w6[2] = M.y; w6[3] = M.z; w6[4] = M.w;
    w6[5] = R.x;
}

// One packed tap-pair: 5 pk ops + 2 exp for 2 pixels.
__device__ __forceinline__ void tap_pair(v2f nb, v2f ce, v2f& nu, v2f& de,
                                         float b, v2f ncr2)
{
    v2f d  = nb - ce;                                   // pk_add
    v2f tt = __builtin_elementwise_fma(d * d, ncr2,
                                       (v2f){b, b});    // pk_mul+pk_fma
    v2f w  = {EXP2(tt.x), EXP2(tt.y)};
    nu = __builtin_elementwise_fma(w, nb, nu);          // pk_fma
    de += w;                                            // pk_add
}

// All horizontal taps of one window row against centers c01/c23.
__device__ __forceinline__ void row_taps(const float* w6, v2f c01, v2f c23,
                                         v2f& n01, v2f& n23, v2f& d01, v2f& d23,
                                         float bm, float b0, float bp,
                                         bool skip0, v2f ncr2)
{
    tap_pair((v2f){w6[0], w6[1]}, c01, n01, d01, bm, ncr2);   // dc=-1
    tap_pair((v2f){w6[2], w6[3]}, c23, n23, d23, bm, ncr2);
    if (!skip0) {
        tap_pair((v2f){w6[1], w6[2]}, c01, n01, d01, b0, ncr2); // dc=0
        tap_pair((v2f){w6[3], w6[4]}, c23, n23, d23, b0, ncr2);
    }
    tap_pair((v2f){w6[2], w6[3]}, c01, n01, d01, bp, ncr2);   // dc=+1
    tap_pair((v2f){w6[4], w6[5]}, c23, n23, d23, bp, ncr2);
}

// Packed 3x3 bilateral core for 4 px: 16 tap-pairs = 80 pk ops + 32 exp.
__device__ __forceinline__ float4 core3x3(const float* wm, const float* wc,
                                          const float* wp,
                                          float nax, float nay, v2f ncr2)
{
    v2f c01 = {wc[1], wc[2]}, c23 = {wc[3], wc[4]};
    v2f n01 = c01, n23 = c23;               // center tap, w == 1
    v2f d01 = {1.f, 1.f}, d23 = {1.f, 1.f};
    const float bd = nax + nay;
    row_taps(wc, c01, c23, n01, n23, d01, d23, nay, 0.0f, nay, true,  ncr2);
    row_taps(wm, c01, c23, n01, n23, d01, d23, bd,  nax,  bd,  false, ncr2);
    row_taps(wp, c01, c23, n01, n23, d01, d23, bd,  nax,  bd,  false, ncr2);
    float4 o;
    o.x = n01.x * RCP(d01.x);
    o.y = n01.y * RCP(d01.y);
    o.z = n23.x * RCP(d23.x);
    o.w = n23.y * RCP(d23.y);
    return o;
}

// Copy replicate-padding into phantom slots of an LDS image.
template<int NR, int NC>
__device__ __forceinline__ void replicate_fill(float* buf, int rlo, int rhi,
                                               int vlo, int vhi, int tid)
{
    if (rlo == 0 && vlo == 0 && rhi == NR - 1 && vhi == NC - 1) return;
    for (int t = tid; t < NR * NC; t += 256) {
        const int r = t / NC, v = t - r * NC;
        const int rs = min(max(r, rlo), rhi);
        const int vs = min(max(v, vlo), vhi);
        if (rs != r || vs != v) buf[r * NC + v] = buf[rs * NC + vs];
    }
}

// Generic LDS-tile pass, 2-row units (8 px), loops over NQ*NRH units.
template<int NQ, int NRH, int SST, int DSTST, bool TOG>
__device__ __forceinline__ void bilat_tile_pass(
    const float* __restrict__ src, float* __restrict__ dst,
    float* __restrict__ gout, int W,
    int tid, float ncr, float nax, float nay, bool prune)
{
    const v2f ncr2 = {ncr, ncr};
    for (int t = tid; t < NQ * NRH; t += 256) {
        const int rp = t / NQ;
        const int q  = t - rp * NQ;
        const int r0 = 2 * rp;
        const float* cp = src + (r0 + 2) * SST + 4 * q + 4;

        if (prune) {
            float w0[6], w1[6], w2[6], w3[6];
            mkrow6(cp - SST,     w0);
            mkrow6(cp,           w1);
            mkrow6(cp + SST,     w2);
            mkrow6(cp + 2 * SST, w3);
            const float4 oA = core3x3(w0, w1, w2, nax, nay, ncr2);
            const float4 oB = core3x3(w1, w2, w3, nax, nay, ncr2);
            if (TOG) {
                *(float4*)(gout + (r0    ) * W + 4 * q) = oA;
                *(float4*)(gout + (r0 + 1) * W + 4 * q) = oB;
            } else {
                *(float4*)(dst + (r0    ) * DSTST + 4 * q) = oA;
                *(float4*)(dst + (r0 + 1) * DSTST + 4 * q) = oB;
            }
        } else {
            #pragma unroll
            for (int rr = 0; rr < 2; ++rr) {
                const float* cp2 = cp + rr * SST;
                const float4 M0 = *(const float4*)cp2;
                float cen[4] = {M0.x, M0.y, M0.z, M0.w};
                float num[4] = {M0.x, M0.y, M0.z, M0.w};
                float den[4] = {1.f, 1.f, 1.f, 1.f};
                #pragma unroll
                for (int dr = -2; dr <= 2; ++dr) {
                    const float ra = (float)(dr * dr) * nax;
                    const float rbest = dr ? ra : nay;
                    if (rbest < TH2) continue;
                    const float* rp2 = cp2 + dr * SST;
                    const float4 Lq = *(const float4*)(rp2 - 4);
                    const float4 Mq = *(const float4*)(rp2);
                    const float4 Rq = *(const float4*)(rp2 + 4);
                    const float w8[8] = {Lq.z, Lq.w, Mq.x, Mq.y, Mq.z, Mq.w,
                                         Rq.x, Rq.y};
                    #pragma unroll
                    for (int dc = -2; dc <= 2; ++dc) {
                        if (dr == 0 && dc == 0) continue;
                        const float b = ra + (float)(dc * dc) * nay;
                        if (b < TH2) continue;
                        #pragma unroll
                        for (int j = 0; j < 4; ++j) {
                            const float nb = w8[2 + j + dc];
                            const float d  = nb - cen[j];
                            const float tt = fmaf(d * d, ncr, b);
                            const float w  = EXP2(tt);
                            num[j] = fmaf(w, nb, num[j]);
                            den[j] += w;
                        }
                    }
                }
                float4 o;
                o.x = num[0] * RCP(den[0]);
                o.y = num[1] * RCP(den[1]);
                o.z = num[2] * RCP(den[2]);
                o.w = num[3] * RCP(den[3]);
                if (TOG) *(float4*)(gout + (r0 + rr) * W + 4 * q) = o;
                else     *(float4*)(dst + (r0 + rr) * DSTST + 4 * q) = o;
            }
        }
    }
}

// Clamped float4 aperture staging: rows [Y0+RO, ...], cols [X0+CO, ...].
template<int NR, int NC, int RO, int CO>
__device__ __forceinline__ void stage_aperture(const float* __restrict__ img,
                                               float* __restrict__ buf,
                                               int Y0, int X0, int H, int W,
                                               int tid)
{
    const int NQ = NC / 4;
    for (int t = tid; t < NR * NQ; t += 256) {
        const int r = t / NQ, k = t - r * NQ;
        const int gy = Y0 + RO + r;
        const int gx = X0 + CO + 4 * k;
        float4 v;
        if (gy >= 0 && gy < H && gx >= 0 && gx + 3 < W) {
            v = *(const float4*)(img + (size_t)gy * W + gx);  // aligned
        } else {
            const size_t rb = (size_t)min(max(gy, 0), H - 1) * W;
            v.x = img[rb + min(max(gx    , 0), W - 1)];
            v.y = img[rb + min(max(gx + 1, 0), W - 1)];
            v.z = img[rb + min(max(gx + 2, 0), W - 1)];
            v.w = img[rb + min(max(gx + 3, 0), W - 1)];
        }
        *(float4*)(buf + r * NC + 4 * k) = v;
    }
}

// =======================================================================
// Kernel A: single bilateral pass (pass 1), no overscan compute.
// =======================================================================

#define PBR 36            // staged rows:  [Y0-2, Y0+33]
#define PBC 76            // staged cols:  [X0-4, X0+71], 304B stride

__global__ __launch_bounds__(256)
void bilat_pass(const float* __restrict__ in, float* __restrict__ out,
                const float* __restrict__ sxyz, const float* __restrict__ srr,
                int p, int H, int W)
{
    __shared__ __align__(16) float buf[PBR * PBC];   // 10944 B

    const int tid = threadIdx.x;
    const int X0 = blockIdx.x * TILE_X;
    const int Y0 = blockIdx.y * TILE_Y;
    const size_t img_off = (size_t)blockIdx.z * (size_t)H * (size_t)W;

    const float L2E = 1.4426950408889634f;
    const float sx = sxyz[2 * p], sy = sxyz[2 * p + 1], sr = srr[p];
    const float ncr = -0.5f / (sr * sr) * L2E;
    const float nax = -0.5f / (sx * sx) * L2E;
    const float nay = -0.5f / (sy * sy) * L2E;
    const bool prune = (4.f * nax < TH2) && (4.f * nay < TH2);

    stage_aperture<PBR, PBC, -2, -4>(in + img_off, buf, Y0, X0, H, W, tid);
    __syncthreads();

    float* gout = out + img_off + (size_t)Y0 * W + X0;
    bilat_tile_pass<TILE_X / 4, TILE_Y / 2, PBC, 0, true>(
        buf, nullptr, gout, W, tid, ncr, nax, nay, prune);
}

// =======================================================================
// Kernel B: fused passes 2+3 (1.17x overscan, one round-trip saved).
// =======================================================================

#define F1R 40            // staged p1 rows: [Y0-4, Y0+35]
#define F1C 84            // staged p1 cols: [X0-8, X0+75], 336B stride
#define F2R 36            // p2 tile rows:   [Y0-2, Y0+33]
#define F2C 76            // p2 tile cols:   [X0-4, X0+71]

__global__ __launch_bounds__(256)
void bilat_pass23(const float* __restrict__ in, float* __restrict__ out,
                  const float* __restrict__ sxyz, const float* __restrict__ srr,
                  int H, int W)
{
    __shared__ __align__(16) float buf1[F1R * F1C];   // 13440 B
    __shared__ __align__(16) float buf2[F2R * F2C];   // 10944 B -> 24.4 KB

    const int tid = threadIdx.x;
    const int X0 = blockIdx.x * TILE_X;
    const int Y0 = blockIdx.y * TILE_Y;
    const size_t img_off = (size_t)blockIdx.z * (size_t)H * (size_t)W;

    const float L2E = 1.4426950408889634f;
    float ncr[2], nax[2], nay[2];
    bool prune[2];
    #pragma unroll
    for (int i = 0; i < 2; ++i) {
        const int p = i + 1;
        const float sx = sxyz[2 * p], sy = sxyz[2 * p + 1], sr = srr[p];
        ncr[i] = -0.5f / (sr * sr) * L2E;
        nax[i] = -0.5f / (sx * sx) * L2E;
        nay[i] = -0.5f / (sy * sy) * L2E;
        prune[i] = (4.f * nax[i] < TH2) && (4.f * nay[i] < TH2);
    }

    // stage p1 aperture (exact replicate padding: in holds the full p1 image)
    stage_aperture<F1R, F1C, -4, -8>(in + img_off, buf1, Y0, X0, H, W, tid);
    __syncthreads();

    // pass 2: buf1 -> buf2 (19 quads x 18 row-pairs = 342 units)
    bilat_tile_pass<F2C / 4, F2R / 2, F1C, F2C, false>(
        buf1, buf2, nullptr, W, tid, ncr[0], nax[0], nay[0], prune[0]);
    __syncthreads();
    replicate_fill<F2R, F2C>(buf2,
        max(0, 2 - Y0), min(F2R - 1, (H - 1) - (Y0 - 2)),
        max(0, 4 - X0), min(F2C - 1, (W - 1) - (X0 - 4)), tid);
    __syncthreads();

    // pass 3: buf2 -> global (exactly 256 units)
    float* gout = out + img_off + (size_t)Y0 * W + X0;
    bilat_tile_pass<TILE_X / 4, TILE_Y / 2, F2C, 0, true>(
        buf2, nullptr, gout, W, tid, ncr[1], nax[1], nay[1], prune[1]);
}

// =======================================================================
// Fallback: fused 3-pass kernel (round-9 code) if workspace is too small.
// =======================================================================

#define S0R 44
#define S0C 92
#define S1R 40
#define S1C 84
#define S2R 36
#define S2C 76

__global__ __launch_bounds__(256)
void bilat3_fused(const float* __restrict__ in, float* __restrict__ out,
                  const float* __restrict__ sxyz, const float* __restrict__ srr,
                  int H, int W)
{
    __shared__ __align__(16) float buf0[S0R * S0C];
    __shared__ __align__(16) float buf1[S1R * S1C];

    const int tid = threadIdx.x;
    const int X0 = blockIdx.x * TILE_X;
    const int Y0 = blockIdx.y * TILE_Y;
    const size_t img_off = (size_t)blockIdx.z * (size_t)H * (size_t)W;

    const float L2E = 1.4426950408889634f;
    float ncr[3], nax[3], nay[3];
    bool prune[3];
    #pragma unroll
    for (int p = 0; p < 3; ++p) {
        const float sx = sxyz[2 * p], sy = sxyz[2 * p + 1], sr = srr[p];
        ncr[p] = -0.5f / (sr * sr) * L2E;
        nax[p] = -0.5f / (sx * sx) * L2E;
        nay[p] = -0.5f / (sy * sy) * L2E;
        prune[p] = (4.f * nax[p] < TH2) && (4.f * nay[p] < TH2);
    }

    stage_aperture<S0R, S0C, -6, -12>(in + img_off, buf0, Y0, X0, H, W, tid);
    __syncthreads();

    bilat_tile_pass<S1C / 4, S1R / 2, S0C, S1C, false>(
        buf0, buf1, nullptr, W, tid, ncr[0], nax[0], nay[0], prune[0]);
    __syncthreads();
    replicate_fill<S1R, S1C>(buf1,
        max(0, 4 - Y0), min(S1R - 1, (H - 1) - (Y0 - 4)),
        max(0, 8 - X0), min(S1C - 1, (W - 1) - (X0 - 8)), tid);
    __syncthreads();

    float* buf2 = buf0;
    bilat_tile_pass<S2C / 4, S2R / 2, S1C, S2C, false>(
        buf1, buf2, nullptr, W, tid, ncr[1], nax[1], nay[1], prune[1]);
    __syncthreads();
    replicate_fill<S2R, S2C>(buf2,
        max(0, 2 - Y0), min(S2R - 1, (H - 1) - (Y0 - 2)),
        max(0, 4 - X0), min(S2C - 1, (W - 1) - (X0 - 4)), tid);
    __syncthreads();

    float* gout = out + img_off + (size_t)Y0 * W + X0;
    bilat_tile_pass<TILE_X / 4, TILE_Y / 2, S2C, 0, true>(
        buf2, nullptr, gout, W, tid, ncr[2], nax[2], nay[2], prune[2]);
}

// =======================================================================

extern "C" void kernel_launch(void* const* d_in, const int* in_sizes, int n_in,
                              void* d_out, int out_size, void* d_ws, size_t ws_size,
                              hipStream_t stream)
{
    const float* x    = (const float*)d_in[0];
    const float* sxyz = (const float*)d_in[1];   // [3,2]
    const float* sr   = (const float*)d_in[2];   // [3]
    float* out = (float*)d_out;

    const int H = 512, W = 512;
    const int BC = in_sizes[0] / (H * W);        // 32

    dim3 block(256);
    dim3 grid(W / TILE_X, H / TILE_Y, BC);       // 8 x 16 x 32 = 4096 blocks

    const size_t need = (size_t)BC * H * W * sizeof(float);
    if (d_ws && ws_size >= need) {
        float* ws = (float*)d_ws;
        // pass 1: in -> ws, fused passes 2+3: ws -> out
        bilat_pass<<<grid, block, 0, stream>>>(x, ws, sxyz, sr, 0, H, W);
        bilat_pass23<<<grid, block, 0, stream>>>(ws, out, sxyz, sr, H, W);
    } else {
        bilat3_fused<<<grid, block, 0, stream>>>(x, out, sxyz, sr, H, W);
    }
}

// Round 4
// 129.761 us; speedup vs baseline: 1.0727x; 1.0727x over previous
//
#include <hip/hip_runtime.h>

// Bilateral 5x5, 3 chained passes. [32,1,512,512] fp32, replicate padding,
// w = exp2(dr^2*nax + dc^2*nay + d^2*ncr).
//
// Round-12: BARRIER-FREE DIRECT-GLOBAL PASSES. Empirical law from rounds
// 9-11: kernel time ~= 21us per pass-equivalent of computed pixels,
// regardless of fusion structure (fused-3 3.98x -> 80us; pass23 2.34x ->
// 53us; clean pass 1.0x -> 21us), while HBM sits at 7-15% of peak. So
// fusion never pays; the lever is per-pass efficiency. VALU-issue floor is
// ~6-9us/pass but VALUBusy was only 53%: the {stage->barrier->compute}
// shape stalls all 4 waves of a block together on vmcnt+barrier. This
// round drops LDS entirely: each thread computes 4 px; its 6-wide window
// per row is ONE aligned float4 + TWO scalar dwords (cols gx-1, gx+4),
// replicate-clamp is branchless min/max on the scalar addresses; 9
// independent global loads issue up front; L1 absorbs the 3x row re-read
// between neighboring threads. No barrier, no staging writes, no
// replicate_fill, no unit loop. Same core3x3 arithmetic -> bit-identical.
//
// Pruning (round 3): taps with spatial log2-weight < TH2 skipped via
// block-uniform branches -> effective 3x3 for sigma=0.5 (8 exps/px).
// Generic 5x5 path kept for large sigma (streaming, cold).

typedef float v2f __attribute__((ext_vector_type(2)));

#define EXP2(x) __builtin_amdgcn_exp2f(x)
#define RCP(x)  __builtin_amdgcn_rcpf(x)
#define TH2 (-10.0f)

// ---------------- shared tap core (validated rounds 8-11) ----------------

// One packed tap-pair: 5 pk ops + 2 exp for 2 pixels.
__device__ __forceinline__ void tap_pair(v2f nb, v2f ce, v2f& nu, v2f& de,
                                         float b, v2f ncr2)
{
    v2f d  = nb - ce;                                   // pk_add
    v2f tt = __builtin_elementwise_fma(d * d, ncr2,
                                       (v2f){b, b});    // pk_mul+pk_fma
    v2f w  = {EXP2(tt.x), EXP2(tt.y)};
    nu = __builtin_elementwise_fma(w, nb, nu);          // pk_fma
    de += w;                                            // pk_add
}

// All horizontal taps of one window row against centers c01/c23.
__device__ __forceinline__ void row_taps(const float* w6, v2f c01, v2f c23,
                                         v2f& n01, v2f& n23, v2f& d01, v2f& d23,
                                         float bm, float b0, float bp,
                                         bool skip0, v2f ncr2)
{
    tap_pair((v2f){w6[0], w6[1]}, c01, n01, d01, bm, ncr2);   // dc=-1
    tap_pair((v2f){w6[2], w6[3]}, c23, n23, d23, bm, ncr2);
    if (!skip0) {
        tap_pair((v2f){w6[1], w6[2]}, c01, n01, d01, b0, ncr2); // dc=0
        tap_pair((v2f){w6[3], w6[4]}, c23, n23, d23, b0, ncr2);
    }
    tap_pair((v2f){w6[2], w6[3]}, c01, n01, d01, bp, ncr2);   // dc=+1
    tap_pair((v2f){w6[4], w6[5]}, c23, n23, d23, bp, ncr2);
}

// Packed 3x3 bilateral core for 4 px: 16 tap-pairs = 80 pk ops + 32 exp.
__device__ __forceinline__ float4 core3x3(const float* wm, const float* wc,
                                          const float* wp,
                                          float nax, float nay, v2f ncr2)
{
    v2f c01 = {wc[1], wc[2]}, c23 = {wc[3], wc[4]};
    v2f n01 = c01, n23 = c23;               // center tap, w == 1
    v2f d01 = {1.f, 1.f}, d23 = {1.f, 1.f};
    const float bd = nax + nay;
    row_taps(wc, c01, c23, n01, n23, d01, d23, nay, 0.0f, nay, true,  ncr2);
    row_taps(wm, c01, c23, n01, n23, d01, d23, bd,  nax,  bd,  false, ncr2);
    row_taps(wp, c01, c23, n01, n23, d01, d23, bd,  nax,  bd,  false, ncr2);
    float4 o;
    o.x = n01.x * RCP(d01.x);
    o.y = n01.y * RCP(d01.y);
    o.z = n23.x * RCP(d23.x);
    o.w = n23.y * RCP(d23.y);
    return o;
}

// =======================================================================
// Round-12 primary path: direct-global pass, no LDS, no barrier.
// =======================================================================

#define DTX 64            // tile 64 x 16 px, 256 threads x 4 px
#define DTY 16

// 6-wide window row: aligned quad [gx..gx+3] + clamped scalars gx-1, gx+4.
__device__ __forceinline__ void ld6(const float* __restrict__ rowp, int gx,
                                    int W, float* w6)
{
    const float4 M = *(const float4*)(rowp + gx);       // 16B aligned
    const float  lw = rowp[max(gx - 1, 0)];             // branchless clamp
    const float  rx = rowp[min(gx + 4, W - 1)];
    w6[0] = lw;  w6[1] = M.x; w6[2] = M.y; w6[3] = M.z; w6[4] = M.w;
    w6[5] = rx;
}

__global__ __launch_bounds__(256)
void bilat_direct(const float* __restrict__ in, float* __restrict__ out,
                  const float* __restrict__ sxyz, const float* __restrict__ srr,
                  int p, int H, int W)
{
    const int tid = threadIdx.x;
    const int q = tid & 15;           // quad 0..15
    const int r = tid >> 4;           // row  0..15
    const int gx = blockIdx.x * DTX + 4 * q;
    const int gy = blockIdx.y * DTY + r;
    const size_t img_off = (size_t)blockIdx.z * (size_t)H * (size_t)W;
    const float* __restrict__ img = in + img_off;

    const float L2E = 1.4426950408889634f;
    const float sx = sxyz[2 * p], sy = sxyz[2 * p + 1], sr = srr[p];
    const float ncr = -0.5f / (sr * sr) * L2E;
    const float nax = -0.5f / (sx * sx) * L2E;
    const float nay = -0.5f / (sy * sy) * L2E;
    const bool prune = (4.f * nax < TH2) && (4.f * nay < TH2);
    const v2f ncr2 = {ncr, ncr};

    float* op = out + img_off + (size_t)gy * W + gx;

    if (prune) {
        // rows gy-1, gy, gy+1 (replicate-clamped row bases, branchless)
        const float* rm = img + (size_t)max(gy - 1, 0)     * W;
        const float* rc = img + (size_t)gy                 * W;
        const float* rp = img + (size_t)min(gy + 1, H - 1) * W;
        float wm[6], wc[6], wp[6];
        ld6(rm, gx, W, wm);                 // 9 independent loads total
        ld6(rc, gx, W, wc);
        ld6(rp, gx, W, wp);
        *(float4*)op = core3x3(wm, wc, wp, nax, nay, ncr2);
    } else {
        // ---- generic 5x5, streaming per row (cold path) ----
        const float4 C = *(const float4*)(img + (size_t)gy * W + gx);
        float cen[4] = {C.x, C.y, C.z, C.w};
        float num[4] = {C.x, C.y, C.z, C.w};
        float den[4] = {1.f, 1.f, 1.f, 1.f};
        #pragma unroll
        for (int dr = -2; dr <= 2; ++dr) {
            const float ra = (float)(dr * dr) * nax;
            const float rbest = dr ? ra : nay;
            if (rbest < TH2) continue;
            const float* rp2 = img + (size_t)min(max(gy + dr, 0), H - 1) * W;
            const float4 Mq = *(const float4*)(rp2 + gx);
            const float w8[8] = {
                rp2[max(gx - 2, 0)], rp2[max(gx - 1, 0)],
                Mq.x, Mq.y, Mq.z, Mq.w,
                rp2[min(gx + 4, W - 1)], rp2[min(gx + 5, W - 1)]};
            #pragma unroll
            for (int dc = -2; dc <= 2; ++dc) {
                if (dr == 0 && dc == 0) continue;
                const float b = ra + (float)(dc * dc) * nay;
                if (b < TH2) continue;
                #pragma unroll
                for (int j = 0; j < 4; ++j) {
                    const float nb = w8[2 + j + dc];
                    const float d  = nb - cen[j];
                    const float tt = fmaf(d * d, ncr, b);
                    const float w  = EXP2(tt);
                    num[j] = fmaf(w, nb, num[j]);
                    den[j] += w;
                }
            }
        }
        float4 o;
        o.x = num[0] * RCP(den[0]);
        o.y = num[1] * RCP(den[1]);
        o.z = num[2] * RCP(den[2]);
        o.w = num[3] * RCP(den[3]);
        *(float4*)op = o;
    }
}

// =======================================================================
// Fallback: fused 3-pass LDS kernel (rounds 9-11 code) if ws too small.
// =======================================================================

#define TILE_X 64
#define TILE_Y 32
#define S0R 44
#define S0C 92
#define S1R 40
#define S1C 84
#define S2R 36
#define S2C 76

__device__ __forceinline__ void mkrow6(const float* p, float* w6)
{
    const float4 L = *(const float4*)(p - 4);
    const float4 M = *(const float4*)(p);
    const float4 R = *(const float4*)(p + 4);
    w6[0] = L.w; w6[1] = M.x; w6[2] = M.y; w6[3] = M.z; w6[4] = M.w;
    w6[5] = R.x;
}

template<int NR, int NC>
__device__ __forceinline__ void replicate_fill(float* buf, int rlo, int rhi,
                                               int vlo, int vhi, int tid)
{
    if (rlo == 0 && vlo == 0 && rhi == NR - 1 && vhi == NC - 1) return;
    for (int t = tid; t < NR * NC; t += 256) {
        const int r = t / NC, v = t - r * NC;
        const int rs = min(max(r, rlo), rhi);
        const int vs = min(max(v, vlo), vhi);
        if (rs != r || vs != v) buf[r * NC + v] = buf[rs * NC + vs];
    }
}

template<int NQ, int NRH, int SST, int DSTST, bool TOG>
__device__ __forceinline__ void bilat_tile_pass(
    const float* __restrict__ src, float* __restrict__ dst,
    float* __restrict__ gout, int W,
    int tid, float ncr, float nax, float nay, bool prune)
{
    const v2f ncr2 = {ncr, ncr};
    for (int t = tid; t < NQ * NRH; t += 256) {
        const int rp = t / NQ;
        const int q  = t - rp * NQ;
        const int r0 = 2 * rp;
        const float* cp = src + (r0 + 2) * SST + 4 * q + 4;

        if (prune) {
            float w0[6], w1[6], w2[6], w3[6];
            mkrow6(cp - SST,     w0);
            mkrow6(cp,           w1);
            mkrow6(cp + SST,     w2);
            mkrow6(cp + 2 * SST, w3);
            const float4 oA = core3x3(w0, w1, w2, nax, nay, ncr2);
            const float4 oB = core3x3(w1, w2, w3, nax, nay, ncr2);
            if (TOG) {
                *(float4*)(gout + (r0    ) * W + 4 * q) = oA;
                *(float4*)(gout + (r0 + 1) * W + 4 * q) = oB;
            } else {
                *(float4*)(dst + (r0    ) * DSTST + 4 * q) = oA;
                *(float4*)(dst + (r0 + 1) * DSTST + 4 * q) = oB;
            }
        } else {
            #pragma unroll
            for (int rr = 0; rr < 2; ++rr) {
                const float* cp2 = cp + rr * SST;
                const float4 M0 = *(const float4*)cp2;
                float cen[4] = {M0.x, M0.y, M0.z, M0.w};
                float num[4] = {M0.x, M0.y, M0.z, M0.w};
                float den[4] = {1.f, 1.f, 1.f, 1.f};
                #pragma unroll
                for (int dr = -2; dr <= 2; ++dr) {
                    const float ra = (float)(dr * dr) * nax;
                    const float rbest = dr ? ra : nay;
                    if (rbest < TH2) continue;
                    const float* rp2 = cp2 + dr * SST;
                    const float4 Lq = *(const float4*)(rp2 - 4);
                    const float4 Mq = *(const float4*)(rp2);
                    const float4 Rq = *(const float4*)(rp2 + 4);
                    const float w8[8] = {Lq.z, Lq.w, Mq.x, Mq.y, Mq.z, Mq.w,
                                         Rq.x, Rq.y};
                    #pragma unroll
                    for (int dc = -2; dc <= 2; ++dc) {
                        if (dr == 0 && dc == 0) continue;
                        const float b = ra + (float)(dc * dc) * nay;
                        if (b < TH2) continue;
                        #pragma unroll
                        for (int j = 0; j < 4; ++j) {
                            const float nb = w8[2 + j + dc];
                            const float d  = nb - cen[j];
                            const float tt = fmaf(d * d, ncr, b);
                            const float w  = EXP2(tt);
                            num[j] = fmaf(w, nb, num[j]);
                            den[j] += w;
                        }
                    }
                }
                float4 o;
                o.x = num[0] * RCP(den[0]);
                o.y = num[1] * RCP(den[1]);
                o.z = num[2] * RCP(den[2]);
                o.w = num[3] * RCP(den[3]);
                if (TOG) *(float4*)(gout + (r0 + rr) * W + 4 * q) = o;
                else     *(float4*)(dst + (r0 + rr) * DSTST + 4 * q) = o;
            }
        }
    }
}

template<int NR, int NC, int RO, int CO>
__device__ __forceinline__ void stage_aperture(const float* __restrict__ img,
                                               float* __restrict__ buf,
                                               int Y0, int X0, int H, int W,
                                               int tid)
{
    const int NQ = NC / 4;
    for (int t = tid; t < NR * NQ; t += 256) {
        const int r = t / NQ, k = t - r * NQ;
        const int gy = Y0 + RO + r;
        const int gx = X0 + CO + 4 * k;
        float4 v;
        if (gy >= 0 && gy < H && gx >= 0 && gx + 3 < W) {
            v = *(const float4*)(img + (size_t)gy * W + gx);
        } else {
            const size_t rb = (size_t)min(max(gy, 0), H - 1) * W;
            v.x = img[rb + min(max(gx    , 0), W - 1)];
            v.y = img[rb + min(max(gx + 1, 0), W - 1)];
            v.z = img[rb + min(max(gx + 2, 0), W - 1)];
            v.w = img[rb + min(max(gx + 3, 0), W - 1)];
        }
        *(float4*)(buf + r * NC + 4 * k) = v;
    }
}

__global__ __launch_bounds__(256)
void bilat3_fused(const float* __restrict__ in, float* __restrict__ out,
                  const float* __restrict__ sxyz, const float* __restrict__ srr,
                  int H, int W)
{
    __shared__ __align__(16) float buf0[S0R * S0C];
    __shared__ __align__(16) float buf1[S1R * S1C];

    const int tid = threadIdx.x;
    const int X0 = blockIdx.x * TILE_X;
    const int Y0 = blockIdx.y * TILE_Y;
    const size_t img_off = (size_t)blockIdx.z * (size_t)H * (size_t)W;

    const float L2E = 1.4426950408889634f;
    float ncr[3], nax[3], nay[3];
    bool prune[3];
    #pragma unroll
    for (int p = 0; p < 3; ++p) {
        const float sx = sxyz[2 * p], sy = sxyz[2 * p + 1], sr = srr[p];
        ncr[p] = -0.5f / (sr * sr) * L2E;
        nax[p] = -0.5f / (sx * sx) * L2E;
        nay[p] = -0.5f / (sy * sy) * L2E;
        prune[p] = (4.f * nax[p] < TH2) && (4.f * nay[p] < TH2);
    }

    stage_aperture<S0R, S0C, -6, -12>(in + img_off, buf0, Y0, X0, H, W, tid);
    __syncthreads();

    bilat_tile_pass<S1C / 4, S1R / 2, S0C, S1C, false>(
        buf0, buf1, nullptr, W, tid, ncr[0], nax[0], nay[0], prune[0]);
    __syncthreads();
    replicate_fill<S1R, S1C>(buf1,
        max(0, 4 - Y0), min(S1R - 1, (H - 1) - (Y0 - 4)),
        max(0, 8 - X0), min(S1C - 1, (W - 1) - (X0 - 8)), tid);
    __syncthreads();

    float* buf2 = buf0;
    bilat_tile_pass<S2C / 4, S2R / 2, S1C, S2C, false>(
        buf1, buf2, nullptr, W, tid, ncr[1], nax[1], nay[1], prune[1]);
    __syncthreads();
    replicate_fill<S2R, S2C>(buf2,
        max(0, 2 - Y0), min(S2R - 1, (H - 1) - (Y0 - 2)),
        max(0, 4 - X0), min(S2C - 1, (W - 1) - (X0 - 4)), tid);
    __syncthreads();

    float* gout = out + img_off + (size_t)Y0 * W + X0;
    bilat_tile_pass<TILE_X / 4, TILE_Y / 2, S2C, 0, true>(
        buf2, nullptr, gout, W, tid, ncr[2], nax[2], nay[2], prune[2]);
}

// =======================================================================

extern "C" void kernel_launch(void* const* d_in, const int* in_sizes, int n_in,
                              void* d_out, int out_size, void* d_ws, size_t ws_size,
                              hipStream_t stream)
{
    const float* x    = (const float*)d_in[0];
    const float* sxyz = (const float*)d_in[1];   // [3,2]
    const float* sr   = (const float*)d_in[2];   // [3]
    float* out = (float*)d_out;

    const int H = 512, W = 512;
    const int BC = in_sizes[0] / (H * W);        // 32

    const size_t img_bytes = (size_t)BC * H * W * sizeof(float);
    if (d_ws && ws_size >= img_bytes) {
        float* ws = (float*)d_ws;
        dim3 block(256);
        dim3 grid(W / DTX, H / DTY, BC);         // 8 x 32 x 32 = 8192 blocks
        // pass 1: in -> out, pass 2: out -> ws, pass 3: ws -> out
        bilat_direct<<<grid, block, 0, stream>>>(x,   out, sxyz, sr, 0, H, W);
        bilat_direct<<<grid, block, 0, stream>>>(out, ws,  sxyz, sr, 1, H, W);
        bilat_direct<<<grid, block, 0, stream>>>(ws,  out, sxyz, sr, 2, H, W);
    } else {
        dim3 block(256);
        dim3 grid(W / TILE_X, H / TILE_Y, BC);   // 8 x 16 x 32 = 4096 blocks
        bilat3_fused<<<grid, block, 0, stream>>>(x, out, sxyz, sr, H, W);
    }
}